// Round 2
// baseline (294.903 us; speedup 1.0000x reference)
//
#include <hip/hip_runtime.h>
#include <hip/hip_bf16.h>
#include <hip/hip_fp16.h>

typedef _Float16 f16x8 __attribute__((ext_vector_type(8)));
typedef _Float16 f16x4 __attribute__((ext_vector_type(4)));
typedef float f32x4 __attribute__((ext_vector_type(4)));

#define MFMA16(a, b, c) __builtin_amdgcn_mfma_f32_16x16x32_f16(a, b, c, 0, 0, 0)

// log2(e) / sqrt(1024)
#define C1 0.045084220027780106f

// ---------------------------------------------------------------------------
// convert f32 -> fp16 for Q, K, Wq, Wk, Wv into one contiguous ws region
// ---------------------------------------------------------------------------
__global__ void cvt_all(const float* __restrict__ Q, const float* __restrict__ K,
                        const float* __restrict__ Wq, const float* __restrict__ Wk,
                        const float* __restrict__ Wv, _Float16* __restrict__ dst) {
    int i = blockIdx.x * blockDim.x + threadIdx.x;  // i indexes groups of 8 f32
    const float* s;
    int off;
    if (i < 524288)       { s = Q;  off = 0;       }
    else if (i < 1048576) { s = K;  off = 524288;  }
    else if (i < 1179648) { s = Wq; off = 1048576; }
    else if (i < 1310720) { s = Wk; off = 1179648; }
    else                  { s = Wv; off = 1310720; }
    int j = i - off;
    float4 a = ((const float4*)s)[2 * j];
    float4 b = ((const float4*)s)[2 * j + 1];
    f16x8 h;
    h[0] = (_Float16)a.x; h[1] = (_Float16)a.y; h[2] = (_Float16)a.z; h[3] = (_Float16)a.w;
    h[4] = (_Float16)b.x; h[5] = (_Float16)b.y; h[6] = (_Float16)b.z; h[7] = (_Float16)b.w;
    ((f16x8*)dst)[i] = h;
}

// ---------------------------------------------------------------------------
// projection GEMM: C[m,n] = sum_k A[m,k] * W[n,k] + bias[n]   (BT gemm)
// z=0: q = Qh*Wq^T, z=1: k = Kh*Wk^T, z=2: v = Kh*Wv^T written TRANSPOSED
//      as vT[b][h][d][n]
// ---------------------------------------------------------------------------
__device__ __forceinline__ void gl_lds16(const void* g, void* l) {
    __builtin_amdgcn_global_load_lds(
        (const __attribute__((address_space(1))) void*)g,
        (__attribute__((address_space(3))) void*)l, 16, 0, 0);
}

__global__ __launch_bounds__(256) void proj_gemm(
    const _Float16* __restrict__ Qh, const _Float16* __restrict__ Kh,
    const _Float16* __restrict__ Wqh, const _Float16* __restrict__ Wkh,
    const _Float16* __restrict__ Wvh,
    const float* __restrict__ bq, const float* __restrict__ bk,
    const float* __restrict__ bv,
    _Float16* __restrict__ qo, _Float16* __restrict__ ko,
    _Float16* __restrict__ vT) {
    const int z = blockIdx.z;
    const _Float16* A = (z == 0) ? Qh : Kh;
    const _Float16* W = (z == 0) ? Wqh : (z == 1 ? Wkh : Wvh);
    const float* bias = (z == 0) ? bq : (z == 1 ? bk : bv);

    __shared__ __align__(16) _Float16 At[128 * 32];
    __shared__ __align__(16) _Float16 Bt[128 * 32];

    const int tid = threadIdx.x;
    const int w = tid >> 6, lane = tid & 63;
    const int g = lane >> 4, c = lane & 15;
    const int m0 = blockIdx.x * 128, n0 = blockIdx.y * 128;
    const int wm = (w & 1) * 64, wn = (w >> 1) * 64;
    const int srow = w * 32 + (lane >> 2);
    const int scol = (lane & 3) * 8;  // in halves

    f32x4 acc[4][4] = {};

    for (int k0 = 0; k0 < 1024; k0 += 32) {
        __syncthreads();
#pragma unroll
        for (int t = 0; t < 2; ++t) {
            int r = srow + t * 16;
            gl_lds16(A + (size_t)(m0 + r) * 1024 + k0 + scol, &At[(w * 2 + t) * 512]);
            gl_lds16(W + (size_t)(n0 + r) * 1024 + k0 + scol, &Bt[(w * 2 + t) * 512]);
        }
        __syncthreads();
        f16x8 af[4], bf[4];
#pragma unroll
        for (int mt = 0; mt < 4; ++mt) af[mt] = *(const f16x8*)&At[(wm + mt * 16 + c) * 32 + g * 8];
#pragma unroll
        for (int nt = 0; nt < 4; ++nt) bf[nt] = *(const f16x8*)&Bt[(wn + nt * 16 + c) * 32 + g * 8];
#pragma unroll
        for (int mt = 0; mt < 4; ++mt)
#pragma unroll
            for (int nt = 0; nt < 4; ++nt)
                acc[mt][nt] = MFMA16(af[mt], bf[nt], acc[mt][nt]);
    }

    if (z != 2) {
        _Float16* C = (z == 0) ? qo : ko;
#pragma unroll
        for (int mt = 0; mt < 4; ++mt)
#pragma unroll
            for (int nt = 0; nt < 4; ++nt) {
                int col = n0 + wn + nt * 16 + c;
                float bb = bias[col];
#pragma unroll
                for (int i = 0; i < 4; ++i) {
                    int row = m0 + wm + mt * 16 + g * 4 + i;
                    C[(size_t)row * 1024 + col] = (_Float16)(acc[mt][nt][i] + bb);
                }
            }
    } else {
#pragma unroll
        for (int mt = 0; mt < 4; ++mt)
#pragma unroll
            for (int nt = 0; nt < 4; ++nt) {
                int col = n0 + wn + nt * 16 + c;
                int hh = col >> 6, dd = col & 63;
                float bb = bias[col];
                int row0 = m0 + wm + mt * 16 + g * 4;
                int bbi = row0 >> 10, nn = row0 & 1023;
                f16x4 pk;
#pragma unroll
                for (int i = 0; i < 4; ++i) pk[i] = (_Float16)(acc[mt][nt][i] + bb);
                *(f16x4*)&vT[((size_t)(bbi * 16 + hh) * 64 + dd) * 1024 + nn] = pk;
            }
    }
}

// ---------------------------------------------------------------------------
// fused attention v2: 1024 threads (16 waves), qtile=32.
// Per block: (q-tile, chunk of 8 (b,h) pairs, avg-group b2), remapped so one
// XCD owns all 32 q-tile blocks of a (chunk,b2) group (K/V stay L2-hot).
// Wave w covers k-range [w*64, w*64+64) for QK^T; softmax with ONE barrier
// (local max+sum, then per-thread 4-wave fixup); P in XOR-swizzled LDS
// (conflict-free writes+reads); PV waves = (q-half, d-tile, k-half) with a
// single 16 KB k-half reduce. A_avg in regs (32/thread), 2 atomic
// contributions/element at the end.
// Register budget: avg 32 + s 32 + qf 16 + transients ~ 115 < 128 -> no spill.
// ---------------------------------------------------------------------------
__global__ __launch_bounds__(1024) void attn(
    const _Float16* __restrict__ qh, const _Float16* __restrict__ kh,
    const _Float16* __restrict__ vT, float* __restrict__ O,
    float* __restrict__ Aavg) {
    extern __shared__ __align__(16) char smem[];
    char* Pb = smem;                           // 65536 B: P[32][1024] f16, swizzled
    float* red_m = (float*)(smem + 65536);     // [16][32]
    float* red_l = red_m + 512;                // [16][32]
    float* Opart = red_l + 512;                // [2][32][66] f32 = 16896 B

    const int tid = threadIdx.x, w = tid >> 6, lane = tid & 63;
    const int g = lane >> 4, c = lane & 15;

    // XCD-aware remap: flat id f, group = f & 7 (one group per XCD),
    // q-tile = f >> 3. Grid is (32, 2, 4) = 256 blocks.
    const int f = blockIdx.x + 32 * (blockIdx.y + 2 * blockIdx.z);
    const int grp = f & 7, q0 = (f >> 3) * 32;
    const int chunk = grp & 1, b2 = grp >> 1;

    // PV wave mapping
    const int qtw = w & 1, dt = (w >> 1) & 3, kh2 = w >> 3;

    float avg[4][2][4] = {};

#pragma unroll 1
    for (int p = 0; p < 8; ++p) {
        const int m = b2 * 16 + chunk * 8 + p;
        const int b = m & 3, h = m >> 2;
        const _Float16* qb = qh + (size_t)b * 1048576 + h * 64;
        const _Float16* kb = kh + (size_t)b * 1048576 + h * 64;
        const _Float16* vb = vT + (size_t)(b * 16 + h) * 65536;

        // Q fragments (B-operand): 2 q-subtiles x 2 d-halves
        f16x8 qf[2][2];
#pragma unroll
        for (int qt = 0; qt < 2; ++qt)
#pragma unroll
            for (int ds = 0; ds < 2; ++ds)
                qf[qt][ds] = *(const f16x8*)(qb + (size_t)(q0 + qt * 16 + c) * 1024 + ds * 32 + g * 8);

        // ---- QK^T: S^T fragments (row=k-local, col=q-local), k in [w*64, w*64+64)
        f32x4 s[4][2];
#pragma unroll
        for (int kt = 0; kt < 4; ++kt) {
            const _Float16* kr = kb + (size_t)(w * 64 + kt * 16 + c) * 1024 + g * 8;
            f16x8 kf0 = *(const f16x8*)kr;
            f16x8 kf1 = *(const f16x8*)(kr + 32);
#pragma unroll
            for (int qt = 0; qt < 2; ++qt) {
                f32x4 z = {0.f, 0.f, 0.f, 0.f};
                z = MFMA16(kf0, qf[qt][0], z);
                s[kt][qt] = MFMA16(kf1, qf[qt][1], z);
            }
        }

        // ---- local (per-wave) max ----
        float pm0 = -3.0e38f, pm1 = -3.0e38f;
#pragma unroll
        for (int kt = 0; kt < 4; ++kt)
#pragma unroll
            for (int i = 0; i < 4; ++i) {
                pm0 = fmaxf(pm0, s[kt][0][i]);
                pm1 = fmaxf(pm1, s[kt][1][i]);
            }
        pm0 = fmaxf(pm0, __shfl_xor(pm0, 16, 64));
        pm0 = fmaxf(pm0, __shfl_xor(pm0, 32, 64));
        pm1 = fmaxf(pm1, __shfl_xor(pm1, 16, 64));
        pm1 = fmaxf(pm1, __shfl_xor(pm1, 32, 64));

        // ---- local exp + local sum (overwrite s with e = exp2((s-pm)*C1)) ----
        float l0 = 0.f, l1 = 0.f;
#pragma unroll
        for (int kt = 0; kt < 4; ++kt)
#pragma unroll
            for (int i = 0; i < 4; ++i) {
                float e0 = exp2f((s[kt][0][i] - pm0) * C1);
                float e1 = exp2f((s[kt][1][i] - pm1) * C1);
                s[kt][0][i] = e0; l0 += e0;
                s[kt][1][i] = e1; l1 += e1;
            }
        l0 += __shfl_xor(l0, 16, 64); l0 += __shfl_xor(l0, 32, 64);
        l1 += __shfl_xor(l1, 16, 64); l1 += __shfl_xor(l1, 32, 64);
        if (g == 0) {
            red_m[w * 32 + c] = pm0;      red_m[w * 32 + 16 + c] = pm1;
            red_l[w * 32 + c] = l0;       red_l[w * 32 + 16 + c] = l1;
        }
        __syncthreads();  // barrier A

        // ---- global fixup: each thread handles 4 waves, then xor-reduce over g
        float mr0[4], lr0[4], mr1[4], lr1[4];
        float M0 = -3.0e38f, M1 = -3.0e38f;
#pragma unroll
        for (int t = 0; t < 4; ++t) {
            int wv = g * 4 + t;
            mr0[t] = red_m[wv * 32 + c];      lr0[t] = red_l[wv * 32 + c];
            mr1[t] = red_m[wv * 32 + 16 + c]; lr1[t] = red_l[wv * 32 + 16 + c];
            M0 = fmaxf(M0, mr0[t]); M1 = fmaxf(M1, mr1[t]);
        }
        M0 = fmaxf(M0, __shfl_xor(M0, 16, 64)); M0 = fmaxf(M0, __shfl_xor(M0, 32, 64));
        M1 = fmaxf(M1, __shfl_xor(M1, 16, 64)); M1 = fmaxf(M1, __shfl_xor(M1, 32, 64));
        float L0 = 0.f, L1 = 0.f;
#pragma unroll
        for (int t = 0; t < 4; ++t) {
            L0 += lr0[t] * exp2f((mr0[t] - M0) * C1);
            L1 += lr1[t] * exp2f((mr1[t] - M1) * C1);
        }
        L0 += __shfl_xor(L0, 16, 64); L0 += __shfl_xor(L0, 32, 64);
        L1 += __shfl_xor(L1, 16, 64); L1 += __shfl_xor(L1, 32, 64);
        float sc0 = exp2f((pm0 - M0) * C1) / L0;
        float sc1 = exp2f((pm1 - M1) * C1) / L1;

        // ---- write normalized P (fp16, swizzled) + accumulate avg ----
#pragma unroll
        for (int kt = 0; kt < 4; ++kt) {
            f16x4 pk0, pk1;
#pragma unroll
            for (int i = 0; i < 4; ++i) {
                float p0 = s[kt][0][i] * sc0;
                float p1 = s[kt][1][i] * sc1;
                pk0[i] = (_Float16)p0; pk1[i] = (_Float16)p1;
                avg[kt][0][i] += p0;  avg[kt][1][i] += p1;
            }
            int k2 = (w * 64 + kt * 16 + g * 4) * 2;
            int off0 = (c * 2048 + k2) ^ ((c & 7) << 4);
            int off1 = ((16 + c) * 2048 + k2) ^ ((c & 7) << 4);
            *(f16x4*)(Pb + off0) = pk0;
            *(f16x4*)(Pb + off1) = pk1;
        }
        __syncthreads();  // barrier B

        // ---- PV: wave = (q-half qtw, d-tile dt, k-half kh2); 16 MFMA ----
        f32x4 o = {0.f, 0.f, 0.f, 0.f};
        const _Float16* vrow = vb + (size_t)(dt * 16 + c) * 1024 + kh2 * 512 + g * 8;
        const int prow = qtw * 16 + c;
#pragma unroll
        for (int ks = 0; ks < 16; ++ks) {
            int off = (prow * 2048 + kh2 * 1024 + ks * 64 + g * 16) ^ ((c & 7) << 4);
            f16x8 pa = *(const f16x8*)(Pb + off);
            f16x8 vf = *(const f16x8*)(vrow + ks * 32);
            o = MFMA16(pa, vf, o);
        }
#pragma unroll
        for (int i = 0; i < 4; ++i)
            Opart[(kh2 * 32 + qtw * 16 + g * 4 + i) * 66 + dt * 16 + c] = o[i];
        __syncthreads();  // barrier C

        // ---- reduce k-halves, store O ----
        {
            int qq = tid >> 5, dd = (tid & 31) * 2;
            float2 a0 = *(float2*)&Opart[qq * 66 + dd];
            float2 a1 = *(float2*)&Opart[2112 + qq * 66 + dd];
            float2 r; r.x = a0.x + a1.x; r.y = a0.y + a1.y;
            *(float2*)(O + (size_t)b * 1048576 + (size_t)(q0 + qq) * 1024 + h * 64 + dd) = r;
        }
    }

    // ---- A_avg: one atomic per element, 2 contributions total ----
    float* Ab = Aavg + (size_t)b2 * 1048576 + (size_t)q0 * 1024;
#pragma unroll
    for (int kt = 0; kt < 4; ++kt)
#pragma unroll
        for (int qt = 0; qt < 2; ++qt) {
            int qq = qt * 16 + c;
            int kk = w * 64 + kt * 16 + g * 4;
#pragma unroll
            for (int i = 0; i < 4; ++i)
                __hip_atomic_fetch_add(&Ab[(size_t)qq * 1024 + kk + i], avg[kt][qt][i] * 0.0625f,
                                       __ATOMIC_RELAXED, __HIP_MEMORY_SCOPE_AGENT);
        }
}

// ---------------------------------------------------------------------------
extern "C" void kernel_launch(void* const* d_in, const int* in_sizes, int n_in,
                              void* d_out, int out_size, void* d_ws, size_t ws_size,
                              hipStream_t stream) {
    if (ws_size < ((size_t)46 << 20)) return;  // need 46 MB scratch

    const float* Q  = (const float*)d_in[0];
    const float* K  = (const float*)d_in[1];
    const float* Wq = (const float*)d_in[2];
    const float* bq = (const float*)d_in[3];
    const float* Wk = (const float*)d_in[4];
    const float* bk = (const float*)d_in[5];
    const float* Wv = (const float*)d_in[6];
    const float* bv = (const float*)d_in[7];

    char* ws = (char*)d_ws;
    _Float16* Qh  = (_Float16*)(ws);                      //  8 MB
    _Float16* Kh  = (_Float16*)(ws + ((size_t)8 << 20));  //  8 MB
    _Float16* Wqh = (_Float16*)(ws + ((size_t)16 << 20)); //  2 MB
    _Float16* Wkh = (_Float16*)(ws + ((size_t)18 << 20)); //  2 MB
    _Float16* Wvh = (_Float16*)(ws + ((size_t)20 << 20)); //  2 MB
    _Float16* qo  = (_Float16*)(ws + ((size_t)22 << 20)); //  8 MB
    _Float16* ko  = (_Float16*)(ws + ((size_t)30 << 20)); //  8 MB
    _Float16* vT  = (_Float16*)(ws + ((size_t)38 << 20)); //  8 MB

    float* O = (float*)d_out;
    float* Aavg = O + (size_t)4 * 1024 * 1024;

    // 1) convert inputs to fp16 (dst region is contiguous: Qh..Wvh)
    cvt_all<<<dim3(1441792 / 256), 256, 0, stream>>>(Q, K, Wq, Wk, Wv, Qh);

    // 2) three projection GEMMs in one launch (z selects)
    proj_gemm<<<dim3(32, 8, 3), 256, 0, stream>>>(Qh, Kh, Wqh, Wkh, Wvh,
                                                  bq, bk, bv, qo, ko, vT);

    // 3) zero A_avg output region (2 atomic contributions land on it)
    hipMemsetAsync(Aavg, 0, (size_t)4 * 1024 * 1024 * sizeof(float), stream);

    // 4) fused attention
    const int SMEM = 65536 + 2048 + 2048 + 2 * 32 * 66 * 4;  // 86528
    hipFuncSetAttribute((const void*)attn, hipFuncAttributeMaxDynamicSharedMemorySize, SMEM);
    attn<<<dim3(32, 2, 4), 1024, SMEM, stream>>>(qo, ko, vT, O, Aavg);
}

// Round 3
// 184.240 us; speedup vs baseline: 1.6006x; 1.6006x over previous
//
#include <hip/hip_runtime.h>
#include <hip/hip_bf16.h>
#include <hip/hip_fp16.h>

typedef _Float16 f16x8 __attribute__((ext_vector_type(8)));
typedef _Float16 f16x4 __attribute__((ext_vector_type(4)));
typedef _Float16 f16x2 __attribute__((ext_vector_type(2)));
typedef float f32x4 __attribute__((ext_vector_type(4)));
typedef float f32x16 __attribute__((ext_vector_type(16)));
typedef unsigned int u32x4 __attribute__((ext_vector_type(4)));

#define MFMA16(a, b, c) __builtin_amdgcn_mfma_f32_16x16x32_f16(a, b, c, 0, 0, 0)
#define MFMA32(a, b, c) __builtin_amdgcn_mfma_f32_32x32x16_f16(a, b, c, 0, 0, 0)

// log2(e) / sqrt(1024)
#define C1 0.045084220027780106f

// ---------------------------------------------------------------------------
// convert f32 -> fp16 for Q, K, Wq, Wk, Wv into one contiguous ws region
// ---------------------------------------------------------------------------
__global__ void cvt_all(const float* __restrict__ Q, const float* __restrict__ K,
                        const float* __restrict__ Wq, const float* __restrict__ Wk,
                        const float* __restrict__ Wv, _Float16* __restrict__ dst) {
    int i = blockIdx.x * blockDim.x + threadIdx.x;  // i indexes groups of 8 f32
    const float* s;
    int off;
    if (i < 524288)       { s = Q;  off = 0;       }
    else if (i < 1048576) { s = K;  off = 524288;  }
    else if (i < 1179648) { s = Wq; off = 1048576; }
    else if (i < 1310720) { s = Wk; off = 1179648; }
    else                  { s = Wv; off = 1310720; }
    int j = i - off;
    float4 a = ((const float4*)s)[2 * j];
    float4 b = ((const float4*)s)[2 * j + 1];
    f16x8 h;
    h[0] = (_Float16)a.x; h[1] = (_Float16)a.y; h[2] = (_Float16)a.z; h[3] = (_Float16)a.w;
    h[4] = (_Float16)b.x; h[5] = (_Float16)b.y; h[6] = (_Float16)b.z; h[7] = (_Float16)b.w;
    ((f16x8*)dst)[i] = h;
}

// ---------------------------------------------------------------------------
// projection GEMM (unchanged from round 1): C[m,n] = A[m,:]·W[n,:] + bias[n]
// z=0: q, z=1: k, z=2: v written transposed as vT[b][h][d][n]
// ---------------------------------------------------------------------------
__device__ __forceinline__ void gl_lds16(const void* g, void* l) {
    __builtin_amdgcn_global_load_lds(
        (const __attribute__((address_space(1))) void*)g,
        (__attribute__((address_space(3))) void*)l, 16, 0, 0);
}

__global__ __launch_bounds__(256) void proj_gemm(
    const _Float16* __restrict__ Qh, const _Float16* __restrict__ Kh,
    const _Float16* __restrict__ Wqh, const _Float16* __restrict__ Wkh,
    const _Float16* __restrict__ Wvh,
    const float* __restrict__ bq, const float* __restrict__ bk,
    const float* __restrict__ bv,
    _Float16* __restrict__ qo, _Float16* __restrict__ ko,
    _Float16* __restrict__ vT) {
    const int z = blockIdx.z;
    const _Float16* A = (z == 0) ? Qh : Kh;
    const _Float16* W = (z == 0) ? Wqh : (z == 1 ? Wkh : Wvh);
    const float* bias = (z == 0) ? bq : (z == 1 ? bk : bv);

    __shared__ __align__(16) _Float16 At[128 * 32];
    __shared__ __align__(16) _Float16 Bt[128 * 32];

    const int tid = threadIdx.x;
    const int w = tid >> 6, lane = tid & 63;
    const int g = lane >> 4, c = lane & 15;
    const int m0 = blockIdx.x * 128, n0 = blockIdx.y * 128;
    const int wm = (w & 1) * 64, wn = (w >> 1) * 64;
    const int srow = w * 32 + (lane >> 2);
    const int scol = (lane & 3) * 8;  // in halves

    f32x4 acc[4][4] = {};

    for (int k0 = 0; k0 < 1024; k0 += 32) {
        __syncthreads();
#pragma unroll
        for (int t = 0; t < 2; ++t) {
            int r = srow + t * 16;
            gl_lds16(A + (size_t)(m0 + r) * 1024 + k0 + scol, &At[(w * 2 + t) * 512]);
            gl_lds16(W + (size_t)(n0 + r) * 1024 + k0 + scol, &Bt[(w * 2 + t) * 512]);
        }
        __syncthreads();
        f16x8 af[4], bf[4];
#pragma unroll
        for (int mt = 0; mt < 4; ++mt) af[mt] = *(const f16x8*)&At[(wm + mt * 16 + c) * 32 + g * 8];
#pragma unroll
        for (int nt = 0; nt < 4; ++nt) bf[nt] = *(const f16x8*)&Bt[(wn + nt * 16 + c) * 32 + g * 8];
#pragma unroll
        for (int mt = 0; mt < 4; ++mt)
#pragma unroll
            for (int nt = 0; nt < 4; ++nt)
                acc[mt][nt] = MFMA16(af[mt], bf[nt], acc[mt][nt]);
    }

    if (z != 2) {
        _Float16* C = (z == 0) ? qo : ko;
#pragma unroll
        for (int mt = 0; mt < 4; ++mt)
#pragma unroll
            for (int nt = 0; nt < 4; ++nt) {
                int col = n0 + wn + nt * 16 + c;
                float bb = bias[col];
#pragma unroll
                for (int i = 0; i < 4; ++i) {
                    int row = m0 + wm + mt * 16 + g * 4 + i;
                    C[(size_t)row * 1024 + col] = (_Float16)(acc[mt][nt][i] + bb);
                }
            }
    } else {
#pragma unroll
        for (int mt = 0; mt < 4; ++mt)
#pragma unroll
            for (int nt = 0; nt < 4; ++nt) {
                int col = n0 + wn + nt * 16 + c;
                int hh = col >> 6, dd = col & 63;
                float bb = bias[col];
                int row0 = m0 + wm + mt * 16 + g * 4;
                int bbi = row0 >> 10, nn = row0 & 1023;
                f16x4 pk;
#pragma unroll
                for (int i = 0; i < 4; ++i) pk[i] = (_Float16)(acc[mt][nt][i] + bb);
                *(f16x4*)&vT[((size_t)(bbi * 16 + hh) * 64 + dd) * 1024 + nn] = pk;
            }
    }
}

// ---------------------------------------------------------------------------
// fused attention v3: 1024 threads (16 waves), 32x32x16 MFMA, in-register P.
// Swapped QK^T (A=K rows=k, B=Q cols=q) -> D: q = lane&31, k = (r&3)+8*(r>>2)+4*hi.
// PV A-fragment needs q = lane&31 (same!), k = hi*8+j -> one shfl_xor(32) of
// packed f16 pairs redistributes (reg = (j&3)+4*(hi+2ks), partner holds j^4).
// No P LDS round-trip. O partials (wave = 64-k chunk) reduced via 132 KB LDS.
// A_avg in regs, staged via LDS for coalesced atomics (2 contribs/elem).
// ---------------------------------------------------------------------------
__global__ __launch_bounds__(1024, 4) void attn(
    const _Float16* __restrict__ qh, const _Float16* __restrict__ kh,
    const _Float16* __restrict__ vT, float* __restrict__ O,
    float* __restrict__ Aavg) {
    extern __shared__ __align__(16) char smem[];
    float* Obuf = (float*)smem;                 // [16][32][66] f32 = 135168 B
    float* red_m = (float*)(smem + 135168);     // [16][32]
    float* red_l = red_m + 512;                 // [16][32]

    const int tid = threadIdx.x, w = tid >> 6, lane = tid & 63;
    const int q5 = lane & 31, hi = lane >> 5;

    // XCD-aware remap: group = f & 7 (one avg-group-half per XCD)
    const int f = blockIdx.x + 32 * (blockIdx.y + 2 * blockIdx.z);
    const int grp = f & 7, q0 = (f >> 3) * 32;
    const int chunk = grp & 1, b2 = grp >> 1;

    float avg[2][16] = {};  // [kt][reg]: q = lane&31, k = w*64+kt*32+(r&3)+4*hi+8*(r>>2)

#pragma unroll 1
    for (int p = 0; p < 8; ++p) {
        const int m = b2 * 16 + chunk * 8 + p;
        const int b = m & 3, h = m >> 2;
        const _Float16* qb = qh + (size_t)b * 1048576 + h * 64;
        const _Float16* kb = kh + (size_t)b * 1048576 + h * 64;
        const _Float16* vb = vT + (size_t)(b * 16 + h) * 65536;

        // ---- QK^T: S^T = K·Q^T, k-range [w*64, w*64+64), 2 kt blocks ----
        f32x16 s[2];
        {
            f16x8 qf[4];
#pragma unroll
            for (int dc = 0; dc < 4; ++dc)
                qf[dc] = *(const f16x8*)(qb + (size_t)(q0 + q5) * 1024 + dc * 16 + hi * 8);
#pragma unroll
            for (int kt = 0; kt < 2; ++kt) {
                f32x16 acc = {};
                const _Float16* krow = kb + (size_t)(w * 64 + kt * 32 + q5) * 1024 + hi * 8;
#pragma unroll
                for (int dc = 0; dc < 4; ++dc) {
                    f16x8 kf = *(const f16x8*)(krow + dc * 16);
                    acc = MFMA32(kf, qf[dc], acc);
                }
                s[kt] = acc;
            }
        }

        // ---- softmax: local (wave) max + sum ----
        float pm = -3.0e38f;
#pragma unroll
        for (int kt = 0; kt < 2; ++kt)
#pragma unroll
            for (int r = 0; r < 16; ++r) pm = fmaxf(pm, s[kt][r]);
        pm = fmaxf(pm, __shfl_xor(pm, 32, 64));
        float l = 0.f;
#pragma unroll
        for (int kt = 0; kt < 2; ++kt)
#pragma unroll
            for (int r = 0; r < 16; ++r) {
                float e = exp2f((s[kt][r] - pm) * C1);
                s[kt][r] = e; l += e;
            }
        l += __shfl_xor(l, 32, 64);
        if (hi == 0) { red_m[w * 32 + q5] = pm; red_l[w * 32 + q5] = l; }
        __syncthreads();  // A

        // ---- global fixup over 16 waves (8 per half, shfl combine) ----
        float mr[8], lr[8], M = -3.0e38f;
#pragma unroll
        for (int t = 0; t < 8; ++t) {
            mr[t] = red_m[(hi * 8 + t) * 32 + q5];
            lr[t] = red_l[(hi * 8 + t) * 32 + q5];
            M = fmaxf(M, mr[t]);
        }
        M = fmaxf(M, __shfl_xor(M, 32, 64));
        float L = 0.f;
#pragma unroll
        for (int t = 0; t < 8; ++t) L += lr[t] * exp2f((mr[t] - M) * C1);
        L += __shfl_xor(L, 32, 64);
        const float sc = exp2f((pm - M) * C1) / L;

        // ---- PV: pack P to f16 pairs, half-wave exchange, 8 MFMAs ----
        f32x16 o0 = {}, o1 = {};
#pragma unroll
        for (int kt = 0; kt < 2; ++kt) {
            unsigned pw[8];
#pragma unroll
            for (int r = 0; r < 8; ++r) {
                float p0 = s[kt][2 * r] * sc;
                float p1 = s[kt][2 * r + 1] * sc;
                avg[kt][2 * r] += p0; avg[kt][2 * r + 1] += p1;
                f16x2 t2; t2[0] = (_Float16)p0; t2[1] = (_Float16)p1;
                pw[r] = __builtin_bit_cast(unsigned, t2);
            }
            // exchange: partner half holds the j^4 elements (same reg indices)
            unsigned recv[2][2];
#pragma unroll
            for (int ks = 0; ks < 2; ++ks)
#pragma unroll
                for (int d = 0; d < 2; ++d) {
                    unsigned send = hi ? pw[4 * ks + d] : pw[4 * ks + 2 + d];
                    recv[ks][d] = (unsigned)__shfl_xor((int)send, 32, 64);
                }
#pragma unroll
            for (int ks = 0; ks < 2; ++ks) {
                unsigned own0 = hi ? pw[4 * ks + 2] : pw[4 * ks + 0];
                unsigned own1 = hi ? pw[4 * ks + 3] : pw[4 * ks + 1];
                u32x4 av;
                av[0] = hi ? recv[ks][0] : own0;   // j0,j1 (hi_src=0)
                av[1] = hi ? recv[ks][1] : own1;   // j2,j3
                av[2] = hi ? own0 : recv[ks][0];   // j4,j5 (hi_src=1)
                av[3] = hi ? own1 : recv[ks][1];   // j6,j7
                f16x8 pa = __builtin_bit_cast(f16x8, av);
                const int koff = w * 64 + kt * 32 + ks * 16 + hi * 8;
                f16x8 v0 = *(const f16x8*)(vb + (size_t)(q5) * 1024 + koff);
                f16x8 v1 = *(const f16x8*)(vb + (size_t)(32 + q5) * 1024 + koff);
                o0 = MFMA32(pa, v0, o0);
                o1 = MFMA32(pa, v1, o1);
            }
        }

        // ---- O partials to LDS (conflict-free b32), reduce over 16 waves ----
        float* ob = Obuf + w * 2112;
#pragma unroll
        for (int r = 0; r < 16; ++r) {
            int qq = (r & 3) + 8 * (r >> 2) + 4 * hi;
            ob[qq * 66 + q5] = o0[r];
            ob[qq * 66 + 32 + q5] = o1[r];
        }
        __syncthreads();  // C
        {
            int qq = tid >> 5, dd = (tid & 31) * 2;
            float sx = 0.f, sy = 0.f;
#pragma unroll
            for (int buf = 0; buf < 16; ++buf) {
                float2 v = *(float2*)&Obuf[buf * 2112 + qq * 66 + dd];
                sx += v.x; sy += v.y;
            }
            float2 r2; r2.x = sx; r2.y = sy;
            *(float2*)(O + (size_t)b * 1048576 + (size_t)(q0 + qq) * 1024 + h * 64 + dd) = r2;
        }
        __syncthreads();  // D
    }

    // ---- A_avg: stage per-wave into LDS (stride 65), coalesced atomics ----
    {
        float* ab = Obuf + w * 2112;  // 32*65 = 2080 <= 2112
#pragma unroll
        for (int kt = 0; kt < 2; ++kt)
#pragma unroll
            for (int r = 0; r < 16; ++r) {
                int kk = kt * 32 + (r & 3) + 4 * hi + 8 * (r >> 2);
                ab[q5 * 65 + kk] = avg[kt][r];
            }
        __builtin_amdgcn_s_waitcnt(0);  // own-wave LDS write->read
        float* Ab = Aavg + (size_t)b2 * 1048576 + (size_t)q0 * 1024 + w * 64;
#pragma unroll
        for (int i = 0; i < 32; ++i) {
            float v = ab[i * 65 + lane];
            __hip_atomic_fetch_add(&Ab[(size_t)i * 1024 + lane], v * 0.0625f,
                                   __ATOMIC_RELAXED, __HIP_MEMORY_SCOPE_AGENT);
        }
    }
}

// ---------------------------------------------------------------------------
extern "C" void kernel_launch(void* const* d_in, const int* in_sizes, int n_in,
                              void* d_out, int out_size, void* d_ws, size_t ws_size,
                              hipStream_t stream) {
    if (ws_size < ((size_t)46 << 20)) return;  // need 46 MB scratch

    const float* Q  = (const float*)d_in[0];
    const float* K  = (const float*)d_in[1];
    const float* Wq = (const float*)d_in[2];
    const float* bq = (const float*)d_in[3];
    const float* Wk = (const float*)d_in[4];
    const float* bk = (const float*)d_in[5];
    const float* Wv = (const float*)d_in[6];
    const float* bv = (const float*)d_in[7];

    char* ws = (char*)d_ws;
    _Float16* Qh  = (_Float16*)(ws);                      //  8 MB
    _Float16* Kh  = (_Float16*)(ws + ((size_t)8 << 20));  //  8 MB
    _Float16* Wqh = (_Float16*)(ws + ((size_t)16 << 20)); //  2 MB
    _Float16* Wkh = (_Float16*)(ws + ((size_t)18 << 20)); //  2 MB
    _Float16* Wvh = (_Float16*)(ws + ((size_t)20 << 20)); //  2 MB
    _Float16* qo  = (_Float16*)(ws + ((size_t)22 << 20)); //  8 MB
    _Float16* ko  = (_Float16*)(ws + ((size_t)30 << 20)); //  8 MB
    _Float16* vT  = (_Float16*)(ws + ((size_t)38 << 20)); //  8 MB

    float* O = (float*)d_out;
    float* Aavg = O + (size_t)4 * 1024 * 1024;

    // 1) convert inputs to fp16 (dst region is contiguous: Qh..Wvh)
    cvt_all<<<dim3(1441792 / 256), 256, 0, stream>>>(Q, K, Wq, Wk, Wv, Qh);

    // 2) three projection GEMMs in one launch (z selects)
    proj_gemm<<<dim3(32, 8, 3), 256, 0, stream>>>(Qh, Kh, Wqh, Wkh, Wvh,
                                                  bq, bk, bv, qo, ko, vT);

    // 3) zero A_avg output region (2 atomic contributions land on it)
    hipMemsetAsync(Aavg, 0, (size_t)4 * 1024 * 1024 * sizeof(float), stream);

    // 4) fused attention
    const int SMEM = 135168 + 2048 + 2048;  // 139264 B
    hipFuncSetAttribute((const void*)attn, hipFuncAttributeMaxDynamicSharedMemorySize, SMEM);
    attn<<<dim3(32, 2, 4), 1024, SMEM, stream>>>(qo, ko, vT, O, Aavg);
}